// Round 9
// baseline (220.132 us; speedup 1.0000x reference)
//
#include <hip/hip_runtime.h>

// ---------------------------------------------------------------------------
// ANHPMultiHeadAttention: fused QKV projection + exp-scored causal attention
// B=8, S=1024, FEAT=HID=1024, H=8, DH=128.
//
// R9 changes vs R8 (attn measured 54us, MfmaUtil 12%, chain-bound):
//  - ATTN: Ps LDS round-trip ELIMINATED. MFMA k-order is free -> permute keys
//    kappa(quad*8+j) = {quad*4+j | 16+quad*4+(j-4)} so the PV B-operand is
//    exactly the packed S^T C-layout registers (2 v_perm per 4 elems). vf
//    follows kappa via two ds_read_b64 per d-row (2-way banks = free).
//  - VALU diet: 1/sqrt(128)*log2(e) folded into Wq/bq (first exp = bare
//    v_exp_f32), second exp via __builtin_amdgcn_exp2f, bf16 pack via
//    +0x8000 + v_perm, causal cmp/sel only on the wave-uniform diag tile.
//  - Launches re-fused: prep (cast+transpose), gemm (R5 single dispatch,
//    grid 64x8x3), attn. R8's 6 launches cost ~+15us.
// ---------------------------------------------------------------------------

typedef __bf16 bf16x8 __attribute__((ext_vector_type(8)));
typedef float floatx4 __attribute__((ext_vector_type(4)));
typedef unsigned int u32x4 __attribute__((ext_vector_type(4)));
typedef unsigned long long u64;
typedef u64 u64x2 __attribute__((ext_vector_type(2)));
typedef unsigned short u16;
typedef unsigned int u32;

#define LOG2E 1.4426950408889634f
#define QSCALE 0.12751743f           // (1/sqrt(128)) * log2(e), folded into Wq
#define PSEL 0x07060302u             // v_perm: [hi16(S0), hi16(S1)]

__device__ __forceinline__ u32 pkbf16(float lo, float hi) {  // 2 bf16 in 1 op
  return __builtin_amdgcn_perm(__float_as_uint(hi) + 0x8000u,
                               __float_as_uint(lo) + 0x8000u, PSEL);
}
__device__ __forceinline__ u16 b16(float f) {
  return (u16)((__float_as_uint(f) + 0x8000u) >> 16);
}

// async global->LDS, 16B per lane. LDS dst = wave-uniform base + lane*16.
__device__ __forceinline__ void gld_lds16(const void* g, void* l) {
  __builtin_amdgcn_global_load_lds(
      (const __attribute__((address_space(1))) unsigned*)g,
      (__attribute__((address_space(3))) unsigned*)l, 16, 0, 0);
}

#define MFMA16(a, b, c) __builtin_amdgcn_mfma_f32_16x16x32_bf16(a, b, c, 0, 0, 0)

// ---------------------------------------------------------------------------
// Kernel 1: prep = cast X (blocks 0..8191) + transpose W (blocks 8192..11263)
// Wq additionally scaled by QSCALE (fold attention scale + log2e into Q).
// ---------------------------------------------------------------------------
__global__ __launch_bounds__(256) void prep_kernel(
    const float4* __restrict__ X, u16* __restrict__ Xb,
    const float* __restrict__ Wq, const float* __restrict__ Wk,
    const float* __restrict__ Wv, u16* __restrict__ Wtb) {
  if (blockIdx.x < 8192) {
    unsigned i = blockIdx.x * 256u + threadIdx.x;
    float4 v = X[i];
    uint2 o;
    o.x = pkbf16(v.x, v.y);
    o.y = pkbf16(v.z, v.w);
    *reinterpret_cast<uint2*>(Xb + 4u * i) = o;
  } else {
    const int bid = blockIdx.x - 8192;          // 0..3071
    const int mat = bid >> 10;                  // 1024 blocks per matrix
    const int bx = bid & 31, by = (bid >> 5) & 31;
    const float* W = (mat == 0) ? Wq : (mat == 1) ? Wk : Wv;
    const float ws = (mat == 0) ? QSCALE : 1.0f;
    u16* Wt = Wtb + (size_t)mat * (1024u * 1024u);
    __shared__ u16 tile[32][33];
    const int x = threadIdx.x & 31, y = threadIdx.x >> 5;
    const int kt = bx * 32, nt = by * 32;
#pragma unroll
    for (int i = 0; i < 4; ++i)
      tile[y + 8 * i][x] = b16(W[(size_t)(kt + y + 8 * i) * 1024 + nt + x] * ws);
    __syncthreads();
#pragma unroll
    for (int i = 0; i < 4; ++i)
      Wt[(size_t)(nt + y + 8 * i) * 1024 + kt + x] = tile[x][y + 8 * i];
  }
}

// ---------------------------------------------------------------------------
// Kernel 2: QKV GEMM (R5-proven). 128x128 tile, BK=64, dbuf single-barrier,
// xor8 swizzle (0 conflicts). grid (64,8,3). Q,K -> [B,H,S,DH]; V -> V^T.
// ---------------------------------------------------------------------------
__global__ __launch_bounds__(256, 2) void gemm_qkv_kernel(
    const u16* __restrict__ Xb, const u16* __restrict__ Wtb,
    const float* __restrict__ bq, const float* __restrict__ bk,
    const float* __restrict__ bv, u16* __restrict__ Qh, u16* __restrict__ Kh,
    u16* __restrict__ Vt) {
  const int mat = blockIdx.z;
  const u16* __restrict__ Wt = Wtb + (size_t)mat * (1024u * 1024u);
  const float* __restrict__ bias = (mat == 0) ? bq : (mat == 1) ? bk : bv;
  const float bscale = (mat == 0) ? QSCALE : 1.0f;

  const int m0 = blockIdx.x * 128;
  const int n0 = blockIdx.y * 128;

  __shared__ u16 As[2][128 * 64];   // [m][k] 16KB per buf, 128B rows
  __shared__ u16 Bs[2][128 * 64];   // [n][k]

  const int tid = threadIdx.x;
  const int wid = tid >> 6;
  const int lane = tid & 63;
  const int quad = lane >> 4;
  const int l16 = lane & 15;
  const int wm = (wid & 1) * 64;
  const int wn = (wid >> 1) * 64;

  const floatx4 z4 = {0.f, 0.f, 0.f, 0.f};
  floatx4 acc[4][4];
#pragma unroll
  for (int i = 0; i < 4; ++i)
#pragma unroll
    for (int j = 0; j < 4; ++j) acc[i][j] = z4;

  const int srow = wid * 32;
  const int lrow = lane >> 3;
  const int gblk = (lane & 7) ^ lrow;

  auto stage = [&](int b, int k0) {
#pragma unroll
    for (int c = 0; c < 4; ++c) {
      const int row = srow + c * 8 + lrow;
      gld_lds16(Xb + (size_t)(m0 + row) * 1024 + k0 + gblk * 8,
                As[b] + (srow + c * 8) * 64);
      gld_lds16(Wt + (size_t)(n0 + row) * 1024 + k0 + gblk * 8,
                Bs[b] + (srow + c * 8) * 64);
    }
  };

  stage(0, 0);

  for (int i = 0; i < 16; ++i) {
    __syncthreads();
    if (i < 15) stage((i + 1) & 1, (i + 1) * 64);

    const u16* __restrict__ Ab = As[i & 1];
    const u16* __restrict__ Bb = Bs[i & 1];
#pragma unroll
    for (int c = 0; c < 2; ++c) {
      const int phys = ((c * 4 + quad) ^ (l16 & 7)) * 8;
      bf16x8 af[4], bfr[4];
#pragma unroll
      for (int ii = 0; ii < 4; ++ii)
        af[ii] = *(const bf16x8*)(Ab + (wm + ii * 16 + l16) * 64 + phys);
#pragma unroll
      for (int j = 0; j < 4; ++j)
        bfr[j] = *(const bf16x8*)(Bb + (wn + j * 16 + l16) * 64 + phys);
#pragma unroll
      for (int ii = 0; ii < 4; ++ii)
#pragma unroll
        for (int j = 0; j < 4; ++j)
          acc[ii][j] = MFMA16(af[ii], bfr[j], acc[ii][j]);
    }
  }

  // epilogue. C/D layout: col = l16 (n), row = quad*4 + reg (m).
  const int b = m0 >> 10;
  const int h = n0 >> 7;
  const int sbase = (m0 & 1023) + wm;
  float bv4[4];
#pragma unroll
  for (int j = 0; j < 4; ++j) bv4[j] = bias[n0 + wn + j * 16 + l16] * bscale;

  if (mat < 2) {
    u16* outp = (mat == 0 ? Qh : Kh) + (size_t)(b * 8 + h) * 1024 * 128;
#pragma unroll
    for (int i = 0; i < 4; ++i)
#pragma unroll
      for (int j = 0; j < 4; ++j) {
        const int d = wn + j * 16 + l16;
#pragma unroll
        for (int r = 0; r < 4; ++r) {
          const int s = sbase + i * 16 + quad * 4 + r;
          outp[(size_t)s * 128 + d] = b16(acc[i][j][r] + bv4[j]);
        }
      }
  } else {
    // V^T: out[((b*8+h)*128 + d)*1024 + s]; 4 regs = 4 consecutive s.
    u16* outp = Vt + (size_t)(b * 8 + h) * 128 * 1024;
#pragma unroll
    for (int i = 0; i < 4; ++i)
#pragma unroll
      for (int j = 0; j < 4; ++j) {
        const int d = wn + j * 16 + l16;
        const int s = sbase + i * 16 + quad * 4;
        uint2 pk;
        pk.x = pkbf16(acc[i][j][0] + bv4[j], acc[i][j][1] + bv4[j]);
        pk.y = pkbf16(acc[i][j][2] + bv4[j], acc[i][j][3] + bv4[j]);
        *(uint2*)(outp + (size_t)d * 1024 + s) = pk;
      }
  }
}

// ---------------------------------------------------------------------------
// Kernel 3: attention. grid 512 (64 bh x 8 qtiles of 128), block 256
// (4 waves x 32 q-rows). BK=32, Ks+Vs double-buffered, one barrier/iter.
// NO P LDS round-trip: PV B-operand assembled in-register from packed S^T
// C-layout (key permutation folded into vf's two b64 reads per d-row).
// 32KB LDS. Q pre-scaled by QSCALE -> e = v_exp(st) directly.
// ---------------------------------------------------------------------------
__global__ __launch_bounds__(256, 2) void attn_kernel(const u16* __restrict__ Qh,
                                                      const u16* __restrict__ Kh,
                                                      const u16* __restrict__ Vt,
                                                      float* __restrict__ out) {
  const int id = blockIdx.x;
  const int bh = (id & 7) * 8 + ((id >> 3) & 7);   // XCD x owns 8 heads
  const int QTMAP[8] = {7, 4, 6, 5, 0, 3, 1, 2};   // CU pairs sum equal
  const int qt = QTMAP[id >> 6];
  const int q0 = qt * 128;

  const int tid = threadIdx.x;
  const int wid = tid >> 6;
  const int lane = tid & 63;
  const int quad = lane >> 4;
  const int l16 = lane & 15;

  __shared__ u16 Ks[2][32 * 128];   // [key][d] 256B rows, xor16, 8KB each
  __shared__ u16 Vs[2][128 * 32];   // [d][key] 64B rows, 8KB each

  const u16* __restrict__ Qbase = Qh + (size_t)bh * 1024 * 128;
  const u16* __restrict__ Kbase = Kh + (size_t)bh * 1024 * 128;
  const u16* __restrict__ Vbase = Vt + (size_t)bh * 128 * 1024;

  const int qw = q0 + wid * 32;     // this wave's 32 q-rows

  // Q B-frags (for S^T = MFMA(kf,qf)): lane l16 = q, k = quad*8+j.
  bf16x8 qf[2][4];
#pragma unroll
  for (int nt = 0; nt < 2; ++nt)
#pragma unroll
    for (int c = 0; c < 4; ++c)
      qf[nt][c] = *(const bf16x8*)(Qbase + (size_t)(qw + nt * 16 + l16) * 128 +
                                   c * 32 + quad * 8);

  const floatx4 z4 = {0.f, 0.f, 0.f, 0.f};
  floatx4 o[2][8];
#pragma unroll
  for (int nt = 0; nt < 2; ++nt)
#pragma unroll
    for (int dt = 0; dt < 8; ++dt) o[nt][dt] = z4;
  float lacc[2] = {0.f, 0.f};

  auto stage = [&](int b, int k0) {
    // K: 32 rows x 256B; wave stages 8 rows, 4 rows (1KB)/call, xor16.
#pragma unroll
    for (int c = 0; c < 2; ++c) {
      const int r0 = wid * 8 + c * 4;
      const int row = r0 + quad;
      gld_lds16(Kbase + (size_t)(k0 + row) * 128 + ((l16 ^ (row & 15)) * 8),
                Ks[b] + r0 * 128);
    }
    // V: 128 rows x 64B; wave stages 32 rows, 16 rows (1KB)/call.
#pragma unroll
    for (int c = 0; c < 2; ++c) {
      const int r0 = wid * 32 + c * 16;
      const int row = r0 + (lane >> 2);
      gld_lds16(Vbase + (size_t)row * 1024 + k0 + (lane & 3) * 8,
                Vs[b] + r0 * 32);
    }
  };

  const int n = (q0 + 128) >> 5;    // 32-key iterations: 4..32
  stage(0, 0);

  for (int i = 0; i < n; ++i) {
    const int k0 = i << 5;
    __syncthreads();                // drains prefetch(i); frees buf (i-1)&1
    if (i + 1 < n) stage((i + 1) & 1, k0 + 32);

    if (k0 <= qw + 31) {            // wave-uniform causal live check
      const u16* __restrict__ Kb = Ks[i & 1];
      const u16* __restrict__ Vb = Vs[i & 1];
      const bool diag = (k0 == qw); // wave-uniform: only tile needing masks

      u32 pw[2][4];                 // [nt][k-word]: PV B-operand, packed bf16
#pragma unroll
      for (int f = 0; f < 2; ++f) {
        bf16x8 kf[4];
#pragma unroll
        for (int c = 0; c < 4; ++c)
          kf[c] = *(const bf16x8*)(Kb + (f * 16 + l16) * 128 +
                                   (((c * 4 + quad) ^ l16) * 8));
        floatx4 st[2];
#pragma unroll
        for (int nt = 0; nt < 2; ++nt) {
          st[nt] = z4;
#pragma unroll
          for (int c = 0; c < 4; ++c) st[nt] = MFMA16(kf[c], qf[nt][c], st[nt]);
        }
#pragma unroll
        for (int nt = 0; nt < 2; ++nt) {
          float p[4];
#pragma unroll
          for (int r = 0; r < 4; ++r) {
            const float e = fminf(__builtin_amdgcn_exp2f(st[nt][r]), 85.f);
            p[r] = __builtin_amdgcn_exp2f(e * LOG2E);
          }
          if (diag) {               // mask: key f*16+quad*4+r > q nt*16+l16
#pragma unroll
            for (int r = 0; r < 4; ++r)
              p[r] = (f * 16 + quad * 4 + r > nt * 16 + l16) ? 0.f : p[r];
          }
          lacc[nt] += (p[0] + p[1]) + (p[2] + p[3]);
          pw[nt][f * 2 + 0] = pkbf16(p[0], p[1]);
          pw[nt][f * 2 + 1] = pkbf16(p[2], p[3]);
        }
      }

      // PV: B-operand = packed registers (key perm kappa); A = V^T via 2xb64.
      bf16x8 pa[2];
#pragma unroll
      for (int nt = 0; nt < 2; ++nt) {
        u32x4 t;
        t.x = pw[nt][0]; t.y = pw[nt][1]; t.z = pw[nt][2]; t.w = pw[nt][3];
        pa[nt] = __builtin_bit_cast(bf16x8, t);
      }
#pragma unroll
      for (int dt = 0; dt < 8; ++dt) {
        const int d = dt * 16 + l16;
        u64x2 t;
        t.x = *(const u64*)(Vb + d * 32 + quad * 4);        // keys quad*4..+3
        t.y = *(const u64*)(Vb + d * 32 + 16 + quad * 4);   // keys 16+quad*4..
        const bf16x8 vf = __builtin_bit_cast(bf16x8, t);
        o[0][dt] = MFMA16(vf, pa[0], o[0][dt]);
        o[1][dt] = MFMA16(vf, pa[1], o[1][dt]);
      }
    }
  }

  // l reduce across quads (lanes sharing l16), normalize, store.
  float linv[2];
#pragma unroll
  for (int nt = 0; nt < 2; ++nt) {
    float s = lacc[nt];
    s += __shfl_xor(s, 16);
    s += __shfl_xor(s, 32);
    linv[nt] = 1.0f / s;
  }

  // O^T C-layout: col(l16)=q, row(quad*4+r)=d -> contiguous float4.
  float* outp = out + (size_t)(bh >> 3) * 1024 * 1024 + (bh & 7) * 128;
#pragma unroll
  for (int nt = 0; nt < 2; ++nt) {
    const int qrow = qw + nt * 16 + l16;
#pragma unroll
    for (int dt = 0; dt < 8; ++dt) {
      float4 v;
      v.x = o[nt][dt][0] * linv[nt];
      v.y = o[nt][dt][1] * linv[nt];
      v.z = o[nt][dt][2] * linv[nt];
      v.w = o[nt][dt][3] * linv[nt];
      *(float4*)(outp + (size_t)qrow * 1024 + dt * 16 + quad * 4) = v;
    }
  }
}

// ---------------------------------------------------------------------------
extern "C" void kernel_launch(void* const* d_in, const int* in_sizes, int n_in,
                              void* d_out, int out_size, void* d_ws,
                              size_t ws_size, hipStream_t stream) {
  const float* X = (const float*)d_in[0];
  const float* Wq = (const float*)d_in[1];
  const float* bq = (const float*)d_in[2];
  const float* Wk = (const float*)d_in[3];
  const float* bk = (const float*)d_in[4];
  const float* Wv = (const float*)d_in[5];
  const float* bv = (const float*)d_in[6];
  float* out = (float*)d_out;

  char* ws = (char*)d_ws;
  u16* Xb  = (u16*)(ws);                         // 16 MB  bf16 X
  u16* Wtb = (u16*)(ws + (16u << 20));           //  6 MB  bf16 W^T x3
  u16* Qh  = (u16*)(ws + (22u << 20));           // 16 MB  [B,H,S,DH] (scaled)
  u16* Kh  = (u16*)(ws + (38u << 20));           // 16 MB  [B,H,S,DH]
  u16* Vt  = (u16*)(ws + (54u << 20));           // 16 MB  [B,H,DH,S]

  prep_kernel<<<8192 + 3072, 256, 0, stream>>>((const float4*)X, Xb, Wq, Wk,
                                               Wv, Wtb);
  dim3 gg(64, 8, 3);
  gemm_qkv_kernel<<<gg, 256, 0, stream>>>(Xb, Wtb, bq, bk, bv, Qh, Kh, Vt);
  attn_kernel<<<512, 256, 0, stream>>>(Qh, Kh, Vt, out);
}

// Round 10
// 199.300 us; speedup vs baseline: 1.1045x; 1.1045x over previous
//
#include <hip/hip_runtime.h>

// ---------------------------------------------------------------------------
// ANHPMultiHeadAttention: fused QKV projection + exp-scored causal attention
// B=8, S=1024, FEAT=HID=1024, H=8, DH=128.
//
// R10 changes vs R9 (R8 counters: attn OccupancyPercent 12% = avg 4 waves/CU;
// the qt pairing balanced total work per CU but NOT concurrency -> CUs spend
// most of the kernel with ONE resident block = 1 wave/SIMD, latency-exposed):
//  - ATTN: uniform-work paired blocks. Block pi owns q-tiles qa=pi*64 AND
//    qb=(15-pi)*64 -> exactly 17 key-tiles of compute per block, all 512
//    blocks identical duration -> sustained 2 blocks/CU (8 waves) and zero
//    tail. kf/vf LDS reads shared by both parts (2x MFMA per LDS byte).
//  - ATTN: Vs unit-xor layout (phys 16B unit u holds global unit
//    u ^ ((d>>1)&3)) -> the register-PV's b64 vf reads hit all 32 banks at
//    the 4-phase size floor (R9's flat layout was 8-way conflicted).
//  - Register-PV (no Ps LDS round-trip), exp2 folding, diag-only masking,
//    full-masked-subtile skip all kept from R9. GEMM/prep unchanged (R5).
// ---------------------------------------------------------------------------

typedef __bf16 bf16x8 __attribute__((ext_vector_type(8)));
typedef float floatx4 __attribute__((ext_vector_type(4)));
typedef unsigned int u32x4 __attribute__((ext_vector_type(4)));
typedef unsigned long long u64;
typedef u64 u64x2 __attribute__((ext_vector_type(2)));
typedef unsigned short u16;
typedef unsigned int u32;

#define LOG2E 1.4426950408889634f
#define QSCALE 0.12751743f           // (1/sqrt(128)) * log2(e), folded into Wq
#define PSEL 0x07060302u             // v_perm: [hi16(S0), hi16(S1)]

__device__ __forceinline__ u32 pkbf16(float lo, float hi) {  // 2 bf16, 3 ops
  return __builtin_amdgcn_perm(__float_as_uint(hi) + 0x8000u,
                               __float_as_uint(lo) + 0x8000u, PSEL);
}
__device__ __forceinline__ u16 b16(float f) {
  return (u16)((__float_as_uint(f) + 0x8000u) >> 16);
}

// async global->LDS, 16B per lane. LDS dst = wave-uniform base + lane*16.
__device__ __forceinline__ void gld_lds16(const void* g, void* l) {
  __builtin_amdgcn_global_load_lds(
      (const __attribute__((address_space(1))) unsigned*)g,
      (__attribute__((address_space(3))) unsigned*)l, 16, 0, 0);
}

#define MFMA16(a, b, c) __builtin_amdgcn_mfma_f32_16x16x32_bf16(a, b, c, 0, 0, 0)

// ---------------------------------------------------------------------------
// Kernel 1: prep = cast X (blocks 0..8191) + transpose W (blocks 8192..11263)
// Wq/bq additionally scaled by QSCALE (fold attn scale + log2e into Q).
// ---------------------------------------------------------------------------
__global__ __launch_bounds__(256) void prep_kernel(
    const float4* __restrict__ X, u16* __restrict__ Xb,
    const float* __restrict__ Wq, const float* __restrict__ Wk,
    const float* __restrict__ Wv, u16* __restrict__ Wtb) {
  if (blockIdx.x < 8192) {
    unsigned i = blockIdx.x * 256u + threadIdx.x;
    float4 v = X[i];
    uint2 o;
    o.x = pkbf16(v.x, v.y);
    o.y = pkbf16(v.z, v.w);
    *reinterpret_cast<uint2*>(Xb + 4u * i) = o;
  } else {
    const int bid = blockIdx.x - 8192;          // 0..3071
    const int mat = bid >> 10;                  // 1024 blocks per matrix
    const int bx = bid & 31, by = (bid >> 5) & 31;
    const float* W = (mat == 0) ? Wq : (mat == 1) ? Wk : Wv;
    const float ws = (mat == 0) ? QSCALE : 1.0f;
    u16* Wt = Wtb + (size_t)mat * (1024u * 1024u);
    __shared__ u16 tile[32][33];
    const int x = threadIdx.x & 31, y = threadIdx.x >> 5;
    const int kt = bx * 32, nt = by * 32;
#pragma unroll
    for (int i = 0; i < 4; ++i)
      tile[y + 8 * i][x] = b16(W[(size_t)(kt + y + 8 * i) * 1024 + nt + x] * ws);
    __syncthreads();
#pragma unroll
    for (int i = 0; i < 4; ++i)
      Wt[(size_t)(nt + y + 8 * i) * 1024 + kt + x] = tile[x][y + 8 * i];
  }
}

// ---------------------------------------------------------------------------
// Kernel 2: QKV GEMM (R5-proven, unchanged). 128x128 tile, BK=64, dbuf
// single-barrier, xor8 swizzle (0 conflicts). grid (64,8,3).
// ---------------------------------------------------------------------------
__global__ __launch_bounds__(256, 2) void gemm_qkv_kernel(
    const u16* __restrict__ Xb, const u16* __restrict__ Wtb,
    const float* __restrict__ bq, const float* __restrict__ bk,
    const float* __restrict__ bv, u16* __restrict__ Qh, u16* __restrict__ Kh,
    u16* __restrict__ Vt) {
  const int mat = blockIdx.z;
  const u16* __restrict__ Wt = Wtb + (size_t)mat * (1024u * 1024u);
  const float* __restrict__ bias = (mat == 0) ? bq : (mat == 1) ? bk : bv;
  const float bscale = (mat == 0) ? QSCALE : 1.0f;

  const int m0 = blockIdx.x * 128;
  const int n0 = blockIdx.y * 128;

  __shared__ u16 As[2][128 * 64];   // [m][k] 16KB per buf, 128B rows
  __shared__ u16 Bs[2][128 * 64];   // [n][k]

  const int tid = threadIdx.x;
  const int wid = tid >> 6;
  const int lane = tid & 63;
  const int quad = lane >> 4;
  const int l16 = lane & 15;
  const int wm = (wid & 1) * 64;
  const int wn = (wid >> 1) * 64;

  const floatx4 z4 = {0.f, 0.f, 0.f, 0.f};
  floatx4 acc[4][4];
#pragma unroll
  for (int i = 0; i < 4; ++i)
#pragma unroll
    for (int j = 0; j < 4; ++j) acc[i][j] = z4;

  const int srow = wid * 32;
  const int lrow = lane >> 3;
  const int gblk = (lane & 7) ^ lrow;

  auto stage = [&](int b, int k0) {
#pragma unroll
    for (int c = 0; c < 4; ++c) {
      const int row = srow + c * 8 + lrow;
      gld_lds16(Xb + (size_t)(m0 + row) * 1024 + k0 + gblk * 8,
                As[b] + (srow + c * 8) * 64);
      gld_lds16(Wt + (size_t)(n0 + row) * 1024 + k0 + gblk * 8,
                Bs[b] + (srow + c * 8) * 64);
    }
  };

  stage(0, 0);

  for (int i = 0; i < 16; ++i) {
    __syncthreads();
    if (i < 15) stage((i + 1) & 1, (i + 1) * 64);

    const u16* __restrict__ Ab = As[i & 1];
    const u16* __restrict__ Bb = Bs[i & 1];
#pragma unroll
    for (int c = 0; c < 2; ++c) {
      const int phys = ((c * 4 + quad) ^ (l16 & 7)) * 8;
      bf16x8 af[4], bfr[4];
#pragma unroll
      for (int ii = 0; ii < 4; ++ii)
        af[ii] = *(const bf16x8*)(Ab + (wm + ii * 16 + l16) * 64 + phys);
#pragma unroll
      for (int j = 0; j < 4; ++j)
        bfr[j] = *(const bf16x8*)(Bb + (wn + j * 16 + l16) * 64 + phys);
#pragma unroll
      for (int ii = 0; ii < 4; ++ii)
#pragma unroll
        for (int j = 0; j < 4; ++j)
          acc[ii][j] = MFMA16(af[ii], bfr[j], acc[ii][j]);
    }
  }

  // epilogue. C/D layout: col = l16 (n), row = quad*4 + reg (m).
  const int b = m0 >> 10;
  const int h = n0 >> 7;
  const int sbase = (m0 & 1023) + wm;
  float bv4[4];
#pragma unroll
  for (int j = 0; j < 4; ++j) bv4[j] = bias[n0 + wn + j * 16 + l16] * bscale;

  if (mat < 2) {
    u16* outp = (mat == 0 ? Qh : Kh) + (size_t)(b * 8 + h) * 1024 * 128;
#pragma unroll
    for (int i = 0; i < 4; ++i)
#pragma unroll
      for (int j = 0; j < 4; ++j) {
        const int d = wn + j * 16 + l16;
#pragma unroll
        for (int r = 0; r < 4; ++r) {
          const int s = sbase + i * 16 + quad * 4 + r;
          outp[(size_t)s * 128 + d] = b16(acc[i][j][r] + bv4[j]);
        }
      }
  } else {
    // V^T: out[((b*8+h)*128 + d)*1024 + s]; 4 regs = 4 consecutive s.
    u16* outp = Vt + (size_t)(b * 8 + h) * 128 * 1024;
#pragma unroll
    for (int i = 0; i < 4; ++i)
#pragma unroll
      for (int j = 0; j < 4; ++j) {
        const int d = wn + j * 16 + l16;
        const int s = sbase + i * 16 + quad * 4;
        uint2 pk;
        pk.x = pkbf16(acc[i][j][0] + bv4[j], acc[i][j][1] + bv4[j]);
        pk.y = pkbf16(acc[i][j][2] + bv4[j], acc[i][j][3] + bv4[j]);
        *(uint2*)(outp + (size_t)d * 1024 + s) = pk;
      }
  }
}

// ---------------------------------------------------------------------------
// Kernel 3: attention, uniform paired blocks. grid 512 (8 XCD x 8 bh x 8 pi),
// block 256 (4 waves). Block pi owns q-tiles qa=pi*64 and qb=(15-pi)*64; each
// wave owns 16 rows of each part. Every block = 17 key-tiles of compute ->
// all blocks equal duration, 2/CU sustained, no tail. kf/vf shared by both
// parts. BK=32, Ks+Vs dbuf, one barrier/iter, 32KB LDS. Register-PV; Vs
// unit-xor (b64 vf reads at the 4-phase bank floor). Per-wave causal
// activity; diag-only masking; fully-masked subtile skipped.
// ---------------------------------------------------------------------------
__global__ __launch_bounds__(256, 2) void attn_kernel(const u16* __restrict__ Qh,
                                                      const u16* __restrict__ Kh,
                                                      const u16* __restrict__ Vt,
                                                      float* __restrict__ out) {
  const int id = blockIdx.x;
  const int bh = (id & 7) * 8 + ((id >> 3) & 7);   // XCD x owns 8 heads
  const int pi = id >> 6;                          // 0..7
  const int qa = pi * 64;                          // light part
  const int qb = (15 - pi) * 64;                   // heavy part (qb > qa)

  const int tid = threadIdx.x;
  const int wid = tid >> 6;
  const int lane = tid & 63;
  const int quad = lane >> 4;
  const int l16 = lane & 15;

  __shared__ u16 Ks[2][32 * 128];   // [key][d] 256B rows, xor16, 8KB each
  __shared__ u16 Vs[2][128 * 32];   // [d][key] 64B rows, unit-xor, 8KB each

  const u16* __restrict__ Qbase = Qh + (size_t)bh * 1024 * 128;
  const u16* __restrict__ Kbase = Kh + (size_t)bh * 1024 * 128;
  const u16* __restrict__ Vbase = Vt + (size_t)bh * 128 * 1024;

  const int rP[2] = {qa + wid * 16 + l16, qb + wid * 16 + l16};

  // Q B-frags (S^T = MFMA(kf,qf)): lane l16 = q, k = quad*8+j. Both parts.
  bf16x8 qf[2][4];
#pragma unroll
  for (int P = 0; P < 2; ++P)
#pragma unroll
    for (int c = 0; c < 4; ++c)
      qf[P][c] = *(const bf16x8*)(Qbase + (size_t)rP[P] * 128 + c * 32 +
                                  quad * 8);

  const floatx4 z4 = {0.f, 0.f, 0.f, 0.f};
  floatx4 o[2][8];
#pragma unroll
  for (int P = 0; P < 2; ++P)
#pragma unroll
    for (int dt = 0; dt < 8; ++dt) o[P][dt] = z4;
  float lacc[2] = {0.f, 0.f};

  auto stage = [&](int b, int k0) {
    // K: 32 rows x 256B; wave stages 8 rows, 4 rows (1KB)/call, xor16.
#pragma unroll
    for (int c = 0; c < 2; ++c) {
      const int r0 = wid * 8 + c * 4;
      const int row = r0 + quad;
      gld_lds16(Kbase + (size_t)(k0 + row) * 128 + ((l16 ^ (row & 15)) * 8),
                Ks[b] + r0 * 128);
    }
    // V: 128 rows x 64B; wave stages 32 rows, 16 rows (1KB)/call; phys 16B
    // unit u holds global unit u ^ ((row>>1)&3).
#pragma unroll
    for (int c = 0; c < 2; ++c) {
      const int r0 = wid * 32 + c * 16;
      const int row = r0 + (lane >> 2);
      const int gu = (lane & 3) ^ ((row >> 1) & 3);
      gld_lds16(Vbase + (size_t)row * 1024 + k0 + gu * 8, Vs[b] + r0 * 32);
    }
  };

  // per-wave diagonal key-tile (BK=32) for each part
  const int kd[2] = {qa + (wid >> 1) * 32, qb + (wid >> 1) * 32};
  const int nB = (qb + 64) >> 5;    // staging iterations (18..32)

  // vf slot addresses (u16 units), lane-constant: keys quad*4.., 16+quad*4..
  const int e4 = (l16 >> 1) & 3;
  const int sx = (((((quad >> 1) ^ e4) << 1) | (quad & 1))) * 4;
  const int sy = ((((2 + (quad >> 1)) ^ e4) << 1) | (quad & 1)) * 4;

  stage(0, 0);

  for (int i = 0; i < nB; ++i) {
    const int k0 = i << 5;
    __syncthreads();                // drains prefetch(i); frees buf (i-1)&1
    if (i + 1 < nB) stage((i + 1) & 1, k0 + 32);

    const bool act[2] = {k0 <= kd[0], k0 <= kd[1]};
    if (!act[0] && !act[1]) continue;

    const u16* __restrict__ Kb = Ks[i & 1];
    const u16* __restrict__ Vb = Vs[i & 1];

    u32 pw[2][4];
#pragma unroll
    for (int f = 0; f < 2; ++f) {
      bf16x8 kf[4];
#pragma unroll
      for (int c = 0; c < 4; ++c)
        kf[c] = *(const bf16x8*)(Kb + (f * 16 + l16) * 128 +
                                 (((c * 4 + quad) ^ l16) * 8));
#pragma unroll
      for (int P = 0; P < 2; ++P) {
        if (!act[P]) continue;
        const bool diag = (k0 == kd[P]);
        if (diag && f == 1 && !(wid & 1)) {      // fully masked subtile
          pw[P][2] = 0u; pw[P][3] = 0u;
          continue;
        }
        floatx4 st = z4;
#pragma unroll
        for (int c = 0; c < 4; ++c) st = MFMA16(kf[c], qf[P][c], st);
        float p[4];
#pragma unroll
        for (int r = 0; r < 4; ++r) {
          const float e = fminf(__builtin_amdgcn_exp2f(st[r]), 85.f);
          p[r] = __builtin_amdgcn_exp2f(e * LOG2E);
        }
        if (diag && f == (wid & 1)) {            // diagonal 16x16 subtile
#pragma unroll
          for (int r = 0; r < 4; ++r)
            p[r] = (quad * 4 + r > l16) ? 0.f : p[r];
        }
        lacc[P] += (p[0] + p[1]) + (p[2] + p[3]);
        pw[P][f * 2 + 0] = pkbf16(p[0], p[1]);
        pw[P][f * 2 + 1] = pkbf16(p[2], p[3]);
      }
    }

    // PV: B-operand = packed S^T regs (key perm); A = V^T via 2x b64 (floor).
    bf16x8 pa[2];
#pragma unroll
    for (int P = 0; P < 2; ++P)
      if (act[P]) {
        u32x4 t;
        t.x = pw[P][0]; t.y = pw[P][1]; t.z = pw[P][2]; t.w = pw[P][3];
        pa[P] = __builtin_bit_cast(bf16x8, t);
      }
#pragma unroll
    for (int dt = 0; dt < 8; ++dt) {
      const int d = dt * 16 + l16;
      u64x2 t;
      t.x = *(const u64*)(Vb + d * 32 + sx);     // keys quad*4 .. +3
      t.y = *(const u64*)(Vb + d * 32 + sy);     // keys 16+quad*4 .. +3
      const bf16x8 vf = __builtin_bit_cast(bf16x8, t);
      if (act[0]) o[0][dt] = MFMA16(vf, pa[0], o[0][dt]);
      if (act[1]) o[1][dt] = MFMA16(vf, pa[1], o[1][dt]);
    }
  }

  // l reduce across quads (lanes sharing l16), normalize, store both parts.
  float* outp = out + (size_t)(bh >> 3) * 1024 * 1024 + (bh & 7) * 128;
#pragma unroll
  for (int P = 0; P < 2; ++P) {
    float s = lacc[P];
    s += __shfl_xor(s, 16);
    s += __shfl_xor(s, 32);
    const float linv = 1.0f / s;
#pragma unroll
    for (int dt = 0; dt < 8; ++dt) {
      float4 v;
      v.x = o[P][dt][0] * linv;
      v.y = o[P][dt][1] * linv;
      v.z = o[P][dt][2] * linv;
      v.w = o[P][dt][3] * linv;
      *(float4*)(outp + (size_t)rP[P] * 1024 + dt * 16 + quad * 4) = v;
    }
  }
}

// ---------------------------------------------------------------------------
extern "C" void kernel_launch(void* const* d_in, const int* in_sizes, int n_in,
                              void* d_out, int out_size, void* d_ws,
                              size_t ws_size, hipStream_t stream) {
  const float* X = (const float*)d_in[0];
  const float* Wq = (const float*)d_in[1];
  const float* bq = (const float*)d_in[2];
  const float* Wk = (const float*)d_in[3];
  const float* bk = (const float*)d_in[4];
  const float* Wv = (const float*)d_in[5];
  const float* bv = (const float*)d_in[6];
  float* out = (float*)d_out;

  char* ws = (char*)d_ws;
  u16* Xb  = (u16*)(ws);                         // 16 MB  bf16 X
  u16* Wtb = (u16*)(ws + (16u << 20));           //  6 MB  bf16 W^T x3
  u16* Qh  = (u16*)(ws + (22u << 20));           // 16 MB  [B,H,S,DH] (scaled)
  u16* Kh  = (u16*)(ws + (38u << 20));           // 16 MB  [B,H,S,DH]
  u16* Vt  = (u16*)(ws + (54u << 20));           // 16 MB  [B,H,DH,S]

  prep_kernel<<<8192 + 3072, 256, 0, stream>>>((const float4*)X, Xb, Wq, Wk,
                                               Wv, Wtb);
  dim3 gg(64, 8, 3);
  gemm_qkv_kernel<<<gg, 256, 0, stream>>>(Xb, Wtb, bq, bk, bv, Qh, Kh, Vt);
  attn_kernel<<<512, 256, 0, stream>>>(Qh, Kh, Vt, out);
}